// Round 7
// baseline (59.504 us; speedup 1.0000x reference)
//
#include <hip/hip_runtime.h>

#define NBINS 1536            // 2 * 24 * 32
#define NSUB  8               // one LDS sub-histogram per PAIR of waves (48 KiB, 16 waves/block)
#define HIST_BLOCKS 512       // 2 blocks/CU x 16 waves = 32 waves/CU (full occupancy)
#define HIST_THREADS 1024
#define WAVES_PER_BLOCK (HIST_THREADS / 64)          // 16
#define TOTAL_WAVES (HIST_BLOCKS * WAVES_PER_BLOCK)  // 8192
#define EV_PER_WAVE 256                              // 4 loads x 64 lanes -> 4 KB/wave/step
#define STEP ((size_t)TOTAL_WAVES * EV_PER_WAVE)     // 2,097,152 events per grid sweep
#define RED_BLOCKS 48
#define RED_THREADS 256
#define RED_BINS_PER_BLOCK 32
#define RED_PER_BIN 8

typedef float vfloat4 __attribute__((ext_vector_type(4)));

__device__ __forceinline__ void bin_event(vfloat4 e, unsigned int* sub) {
    // replicate ref bit-exactly: f32 mul by BINS/SENSOR (both fold to 0.05f), trunc, clip
    int xb = (int)(e.x * (32.0f / 640.0f));
    int yb = (int)(e.y * (24.0f / 480.0f));
    xb = min(max(xb, 0), 31);
    yb = min(max(yb, 0), 23);
    int p = (e.w > 0.0f) ? 0 : 768;             // 768 = 24*32
    atomicAdd(&sub[p + (yb << 5) + xb], 1u);
}

__global__ __launch_bounds__(HIST_THREADS)
void event_hist_kernel(const vfloat4* __restrict__ ev, unsigned int* __restrict__ gout, int n) {
    __shared__ unsigned int lh[NSUB * NBINS];   // 48 KiB
    for (int i = threadIdx.x; i < NSUB * NBINS; i += HIST_THREADS) lh[i] = 0u;
    __syncthreads();

    const int lane = threadIdx.x & 63;
    unsigned int* mysub = &lh[(threadIdx.x >> 7) * NBINS];  // 2 waves per sub-histogram

    // wave-contiguous 4 KB bursts: wave gw owns events [gw*256, gw*256+256) each sweep
    const size_t gw   = (size_t)blockIdx.x * WAVES_PER_BLOCK + (threadIdx.x >> 6);
    const size_t base = gw * EV_PER_WAVE + lane;
    const int kmax = (int)((size_t)n / STEP);   // full (unguarded) sweeps

    if (kmax > 0) {
        // software-pipelined: preload next sweep's 4 loads while binning current
        vfloat4 a = ev[base], b = ev[base + 64], c = ev[base + 128], d = ev[base + 192];
        for (int k = 1; k < kmax; ++k) {
            const size_t nb = base + (size_t)k * STEP;
            vfloat4 a2 = ev[nb];
            vfloat4 b2 = ev[nb + 64];
            vfloat4 c2 = ev[nb + 128];
            vfloat4 d2 = ev[nb + 192];
            bin_event(a, mysub); bin_event(b, mysub);
            bin_event(c, mysub); bin_event(d, mysub);
            a = a2; b = b2; c = c2; d = d2;
        }
        bin_event(a, mysub); bin_event(b, mysub);
        bin_event(c, mysub); bin_event(d, mysub);
    }
    // final guarded sweep covers the remainder with the same burst shape
    {
        const size_t nb = base + (size_t)kmax * STEP;
        #pragma unroll
        for (int j = 0; j < 4; ++j) {
            const size_t idx = nb + (size_t)j * 64;
            if (idx < (size_t)n) {
                vfloat4 a = ev[idx];
                bin_event(a, mysub);
            }
        }
    }
    __syncthreads();

    // non-atomic coalesced partials: gout = partial[HIST_BLOCKS][NBINS]
    unsigned int* mypart = gout + (size_t)blockIdx.x * NBINS;
    for (int i2 = threadIdx.x; i2 < NBINS; i2 += HIST_THREADS) {
        unsigned int s = 0;
        #pragma unroll
        for (int c = 0; c < NSUB; ++c) s += lh[c * NBINS + i2];
        mypart[i2] = s;
    }
}

// 48 blocks x 256 threads: 32 bins/block, 8 threads/bin summing 64 partials each
__global__ __launch_bounds__(RED_THREADS)
void reduce_norm_kernel(const unsigned int* __restrict__ partial,
                        float* __restrict__ out, float total) {
    __shared__ unsigned int red[RED_THREADS];
    const int b   = threadIdx.x & (RED_BINS_PER_BLOCK - 1);
    const int j   = threadIdx.x >> 5;                    // [0, 8)
    const int bin = blockIdx.x * RED_BINS_PER_BLOCK + b;
    unsigned int s = 0;
    #pragma unroll 8
    for (int c = j; c < HIST_BLOCKS; c += RED_PER_BIN)
        s += partial[(size_t)c * NBINS + bin];           // coalesced across b
    red[threadIdx.x] = s;
    __syncthreads();
    if (threadIdx.x < RED_BINS_PER_BLOCK) {
        unsigned int t = 0;
        #pragma unroll
        for (int k = 0; k < RED_PER_BIN; ++k) t += red[k * RED_BINS_PER_BLOCK + b];
        out[bin] = (float)t / total;   // exact ints, exact total -> bit-exact vs ref
    }
}

extern "C" void kernel_launch(void* const* d_in, const int* in_sizes, int n_in,
                              void* d_out, int out_size, void* d_ws, size_t ws_size,
                              hipStream_t stream) {
    const vfloat4* ev = (const vfloat4*)d_in[0]; // events [N,4] row-major -> one float4/event
    const int n = in_sizes[0] / 4;
    float* out = (float*)d_out;
    unsigned int* partial = (unsigned int*)d_ws; // 3 MiB of workspace

    event_hist_kernel<<<HIST_BLOCKS, HIST_THREADS, 0, stream>>>(ev, partial, n);
    reduce_norm_kernel<<<RED_BLOCKS, RED_THREADS, 0, stream>>>(partial, out, (float)n);
}